// Round 1
// baseline (298.941 us; speedup 1.0000x reference)
//
#include <hip/hip_runtime.h>

#define L 4096
#define D 512
#define NCH 16   // context n-chunks (256 n per chunk)

typedef __bf16 bf16x8 __attribute__((ext_vector_type(8)));
typedef float  f32x4  __attribute__((ext_vector_type(4)));

__device__ __forceinline__ void load_lds16(const void* g, void* l) {
    __builtin_amdgcn_global_load_lds(
        (const __attribute__((address_space(1))) void*)g,
        (__attribute__((address_space(3))) void*)l, 16, 0, 0);
}

__device__ __forceinline__ void barrier_mem() {
    asm volatile("" ::: "memory");
    __builtin_amdgcn_s_barrier();
    asm volatile("" ::: "memory");
}

// ---------------------------------------------------------------------------
// merged f32 -> bf16 conversion for x, Wqkv, Wout (contiguous dst regions)
// ---------------------------------------------------------------------------
#define NX8  (8 * 4096 * 512 / 8)
#define NW18 (1536 * 512 / 8)
#define NW28 (512 * 512 / 8)
__global__ __launch_bounds__(256) void convert_all(const float* __restrict__ x,
                                                   const float* __restrict__ Wq,
                                                   const float* __restrict__ Wo,
                                                   __bf16* __restrict__ dst) {
    int i = blockIdx.x * 256 + threadIdx.x;
    if (i >= NX8 + NW18 + NW28) return;
    const float* s;
    if (i < NX8)             s = x  + (size_t)i * 8;
    else if (i < NX8 + NW18) s = Wq + (size_t)(i - NX8) * 8;
    else                     s = Wo + (size_t)(i - NX8 - NW18) * 8;
    float4 a = ((const float4*)s)[0], b = ((const float4*)s)[1];
    bf16x8 o = {(__bf16)a.x, (__bf16)a.y, (__bf16)a.z, (__bf16)a.w,
                (__bf16)b.x, (__bf16)b.y, (__bf16)b.z, (__bf16)b.w};
    *(bf16x8*)(dst + (size_t)i * 8) = o;
}

// ---------------------------------------------------------------------------
// 256x256-tile TN bf16 MFMA GEMM, BK=64, 512 threads = 8 waves (2M x 4N).
// C[b][m][n] = sum_k A[b][m][k] * B[b][n][k] (+bias[n]).
// Double-buffered LDS (128 KiB), 4 phases per K-tile:
//   {prefetch 2x global_load_lds | ds_read next subtile | counted lgkm wait |
//    setprio(1) 16xMFMA setprio(0) | raw s_barrier}
// vmcnt counted ONCE per K-tile (vmcnt(2): next-tile's first 2 loads stay in
// flight across the wait). Chunk-XOR swizzle: LDS slot (row,cc) holds global
// k-chunk cc^(row&7); fragment read offset ko = (cq ^ (fr&7))*8.
// ---------------------------------------------------------------------------
template <int M, int N, int K, typename CT>
__global__ __launch_bounds__(512, 2) void gemm_bf16_256(
    const __bf16* __restrict__ A, size_t aStride,
    const __bf16* __restrict__ B, size_t bStride,
    CT* __restrict__ C, size_t cStride,
    const float* __restrict__ bias) {
    __shared__ __align__(16) __bf16 sA[2][256 * 64];
    __shared__ __align__(16) __bf16 sB[2][256 * 64];
    const int b  = blockIdx.z;
    const int m0 = blockIdx.y * 256;
    const int n0 = blockIdx.x * 256;
    const int t    = threadIdx.x;
    const int wave = t >> 6, lane = t & 63;
    const int wm = (wave >> 2) * 128;   // wave M-offset (2 rows of waves)
    const int wn = (wave & 3) * 64;     // wave N-offset (4 cols of waves)
    const int fr = lane & 15, g = lane >> 4;
    const __bf16* Ab = A + (size_t)b * aStride;
    const __bf16* Bb = B + (size_t)b * bStride;
    CT* Cb = C + (size_t)b * cStride;

    f32x4 acc[8][4];
#pragma unroll
    for (int i = 0; i < 8; i++)
#pragma unroll
        for (int j = 0; j < 4; j++) acc[i][j] = (f32x4)(0.0f);

    constexpr int NT = K / 64;

    // one staging call = 2 global_load_lds (one 8KB slice of A-tile + of B-tile)
    auto stage2 = [&](int it, int kt, int pb) {
        const int idx = it * 512 + t;          // 0..2047 chunk index
        const int row = idx >> 3, cc = idx & 7;
        const int scc = cc ^ (row & 7);        // pre-swizzled global source chunk
        const size_t off = (size_t)row * K + (size_t)kt * 64 + scc * 8;
        load_lds16(Ab + (size_t)m0 * K + off, &sA[pb][idx * 8]);
        load_lds16(Bb + (size_t)n0 * K + off, &sB[pb][idx * 8]);
    };
    auto rdA4 = [&](bf16x8* dst, int pb, int ib, int kh) {
#pragma unroll
        for (int i = 0; i < 4; ++i) {
            const int row = wm + (ib + i) * 16 + fr;
            dst[i] = *(const bf16x8*)&sA[pb][row * 64 + (((kh << 2) + g) ^ (fr & 7)) * 8];
        }
    };
    auto rdB4 = [&](bf16x8* dst, int pb, int kh) {
#pragma unroll
        for (int j = 0; j < 4; ++j) {
            const int row = wn + j * 16 + fr;
            dst[j] = *(const bf16x8*)&sB[pb][row * 64 + (((kh << 2) + g) ^ (fr & 7)) * 8];
        }
    };
    auto mm16 = [&](const bf16x8* af, const bf16x8* bfr, int ib) {
        __builtin_amdgcn_s_setprio(1);
#pragma unroll
        for (int i = 0; i < 4; ++i)
#pragma unroll
            for (int j = 0; j < 4; ++j)
                acc[ib + i][j] = __builtin_amdgcn_mfma_f32_16x16x32_bf16(
                    af[i], bfr[j], acc[ib + i][j], 0, 0, 0);
        __builtin_amdgcn_s_setprio(0);
    };

    // prologue: stage K-tile 0 into buffer 0 (8 loads)
#pragma unroll
    for (int it = 0; it < 4; ++it) stage2(it, 0, 0);

    for (int kt = 0; kt < NT; ++kt) {
        const int p = kt & 1;
        const bool pf = (kt + 1 < NT);
        bf16x8 bl[4], bh[4], al[4], ah[4], al2[4], ah2[4];

        // ---- P0: wait for buf p (counted: 2 newest loads stay in flight) ----
        if (pf) {
            stage2(0, kt + 1, p ^ 1);
            asm volatile("s_waitcnt vmcnt(2)" ::: "memory");
        } else {
            asm volatile("s_waitcnt vmcnt(0)" ::: "memory");
        }
        barrier_mem();                       // all waves: buf p fully staged
        rdB4(bl, p, 0);                      // 4 ds_read_b128
        rdA4(al, p, 0, 0);                   // 4
        rdA4(ah, p, 4, 0);                   // 4 (cluster-1 prefetch)
        asm volatile("s_waitcnt lgkmcnt(4)" ::: "memory");   // bl+al ready
        __builtin_amdgcn_sched_barrier(0);
        mm16(al, bl, 0);                     // i 0..3, kh 0
        if (pf) stage2(1, kt + 1, p ^ 1);
        barrier_mem();

        // ---- P1 ----
        rdB4(bh, p, 1);                      // 4
        rdA4(al2, p, 0, 1);                  // 4
        asm volatile("s_waitcnt lgkmcnt(8)" ::: "memory");   // ah ready
        __builtin_amdgcn_sched_barrier(0);
        mm16(ah, bl, 4);                     // i 4..7, kh 0
        if (pf) stage2(2, kt + 1, p ^ 1);
        barrier_mem();

        // ---- P2 ----
        rdA4(ah2, p, 4, 1);                  // 4
        asm volatile("s_waitcnt lgkmcnt(4)" ::: "memory");   // bh+al2 ready
        __builtin_amdgcn_sched_barrier(0);
        mm16(al2, bh, 0);                    // i 0..3, kh 1
        if (pf) stage2(3, kt + 1, p ^ 1);
        barrier_mem();

        // ---- P3 ----
        asm volatile("s_waitcnt lgkmcnt(0)" ::: "memory");   // ah2 ready
        __builtin_amdgcn_sched_barrier(0);
        mm16(ah2, bh, 4);                    // i 4..7, kh 1
        barrier_mem();                       // buf p reads done -> safe to restage
    }

    // epilogue
    const int rb = g * 4;
#pragma unroll
    for (int j = 0; j < 4; ++j) {
        const int n = n0 + wn + j * 16 + fr;
        const float bv = bias ? bias[n] : 0.0f;
#pragma unroll
        for (int i = 0; i < 8; ++i) {
#pragma unroll
            for (int r = 0; r < 4; ++r) {
                const int m = m0 + wm + i * 16 + rb + r;
                Cb[(size_t)m * N + n] = (CT)(acc[i][j][r] + bv);
            }
        }
    }
}

// ---------------------------------------------------------------------------
// k-row stats over bf16 k rows: per row compute (max, 1/sumexp). grid 4096.
// ---------------------------------------------------------------------------
__global__ __launch_bounds__(256) void kstats(const __bf16* __restrict__ qkv,
                                              float2* __restrict__ stats) {
    const int r = blockIdx.x;
    const int b = r >> 9, hc = r & 511;
    const __bf16* row = qkv + (size_t)b * 1536 * L + (size_t)(512 + hc) * L;
    __shared__ float sred[4];
    const int t = threadIdx.x;
    const bf16x8* p = (const bf16x8*)row;
    bf16x8 c0 = p[t * 2], c1 = p[t * 2 + 1];
    float v[16];
    float m = -1e30f;
#pragma unroll
    for (int j = 0; j < 8; j++) {
        v[j] = (float)c0[j];
        v[8 + j] = (float)c1[j];
    }
#pragma unroll
    for (int j = 0; j < 16; j++) m = fmaxf(m, v[j]);
#pragma unroll
    for (int off = 32; off > 0; off >>= 1) m = fmaxf(m, __shfl_down(m, off, 64));
    if ((t & 63) == 0) sred[t >> 6] = m;
    __syncthreads();
    const float m4 = fmaxf(fmaxf(sred[0], sred[1]), fmaxf(sred[2], sred[3]));
    float s = 0.f;
#pragma unroll
    for (int j = 0; j < 16; j++) s += __expf(v[j] - m4);
#pragma unroll
    for (int off = 32; off > 0; off >>= 1) s += __shfl_down(s, off, 64);
    __syncthreads();
    if ((t & 63) == 0) sred[t >> 6] = s;
    __syncthreads();
    if (t == 0) {
        const float stot = sred[0] + sred[1] + sred[2] + sred[3];
        stats[r] = make_float2(m4, 1.0f / stot);
    }
}

// ---------------------------------------------------------------------------
// MFMA context partials: ctxp[chunk][bh][d][e] (f32, d-major) =
//   sum_{n in chunk} exp(k[d,n]-m_d) * v[e,n]   (un-normalized; 1/s at reduce)
// grid (NCH, 64 bh), block 256. Each of 4 waves takes a 64-n K-slice.
// ---------------------------------------------------------------------------
#define SKS 264   // LDS bf16 row stride (256 data + 8 pad)
__global__ __launch_bounds__(256) void context_mfma(const __bf16* __restrict__ qkv,
                                                    const float2* __restrict__ stats,
                                                    float* __restrict__ ctxp) {
    __shared__ __align__(16) __bf16 smem[2 * 64 * SKS];  // 67.6 KB; reused as f32 red[4][4096]
    __shared__ float smax[64];
    __bf16* sk = smem;
    __bf16* sv = smem + 64 * SKS;
    const int chunk = blockIdx.x;
    const int bh = blockIdx.y;
    const int b = bh >> 3, h = bh & 7;
    const __bf16* kbase = qkv + (size_t)b * 1536 * L + (size_t)(512 + h * 64) * L;
    const __bf16* vbase = qkv + (size_t)b * 1536 * L + (size_t)(1024 + h * 64) * L;
    const int t = threadIdx.x;
    if (t < 64) smax[t] = stats[bh * 64 + t].x;
    __syncthreads();

    // stage: thread t -> row d = t>>2, n-quarter (t&3)*64
    {
        const int d = t >> 2, noff = (t & 3) * 64;
        const int n0 = chunk * 256;
        const __bf16* kp = kbase + (size_t)d * L + n0 + noff;
        const __bf16* vp = vbase + (size_t)d * L + n0 + noff;
        const float md = smax[d];
#pragma unroll
        for (int c = 0; c < 8; c++) {
            bf16x8 kk = *(const bf16x8*)(kp + c * 8);
            bf16x8 vv = *(const bf16x8*)(vp + c * 8);
            bf16x8 ek;
#pragma unroll
            for (int j = 0; j < 8; j++) ek[j] = (__bf16)__expf((float)kk[j] - md);
            *(bf16x8*)&sk[d * SKS + noff + c * 8] = ek;
            *(bf16x8*)&sv[d * SKS + noff + c * 8] = vv;
        }
    }
    __syncthreads();

    // MFMA: wave w covers n in [w*64, w*64+64)
    const int wave = t >> 6, lane = t & 63;
    const int fr = lane & 15, kq = (lane >> 4) * 8;
    f32x4 acc[4][4];
#pragma unroll
    for (int i = 0; i < 4; i++)
#pragma unroll
        for (int j = 0; j < 4; j++) acc[i][j] = (f32x4)(0.0f);
#pragma unroll
    for (int kh = 0; kh < 2; kh++) {
        const int koff = wave * 64 + kh * 32 + kq;
        bf16x8 af[4], bfr[4];
#pragma unroll
        for (int i = 0; i < 4; i++) {
            af[i]  = *(const bf16x8*)&sk[(i * 16 + fr) * SKS + koff];
            bfr[i] = *(const bf16x8*)&sv[(i * 16 + fr) * SKS + koff];
        }
#pragma unroll
        for (int i = 0; i < 4; i++)
#pragma unroll
            for (int j = 0; j < 4; j++)
                acc[i][j] = __builtin_amdgcn_mfma_f32_16x16x32_bf16(af[i], bfr[j], acc[i][j], 0, 0, 0);
    }
    __syncthreads();   // MFMA LDS reads done; safe to overwrite smem

    // cross-wave reduce via LDS: red[w][d*64+e] (d = A rows, e = B rows)
    float* red = (float*)smem;   // 4 * 4096 f32 = 64 KB
    const int col = lane & 15, rbase = (lane >> 4) * 4;
#pragma unroll
    for (int i = 0; i < 4; i++)
#pragma unroll
        for (int j = 0; j < 4; j++)
#pragma unroll
            for (int r = 0; r < 4; r++) {
                const int dd = i * 16 + rbase + r;
                const int ee = j * 16 + col;
                red[wave * 4096 + dd * 64 + ee] = acc[i][j][r];
            }
    __syncthreads();
    float* cp = ctxp + ((size_t)chunk * 64 + bh) * 4096;
#pragma unroll
    for (int gg = 0; gg < 4; gg++) {
        const int idx = t * 16 + gg * 4;
        f32x4 s = *(const f32x4*)&red[idx];
        s += *(const f32x4*)&red[4096 + idx];
        s += *(const f32x4*)&red[8192 + idx];
        s += *(const f32x4*)&red[12288 + idx];
        *(f32x4*)&cp[idx] = s;
    }
}

// ---------------------------------------------------------------------------
// reduce ctx partials over chunks, apply 1/s_d, transpose [d][e]->[e][d],
// emit bf16 ctxT[bh][e][d]. grid 256.
// ---------------------------------------------------------------------------
__global__ __launch_bounds__(256) void ctx_reduce(const float* __restrict__ ctxp,
                                                  const float2* __restrict__ stats,
                                                  __bf16* __restrict__ ctxT) {
    const int bh = blockIdx.x >> 2, quarter = blockIdx.x & 3;
    const int t = threadIdx.x;
    const int flat = quarter * 1024 + t * 4;   // d-major: d = flat>>6, e0 = flat&63
    const int d = flat >> 6, e0 = flat & 63;
    f32x4 s = (f32x4)(0.0f);
    for (int ch = 0; ch < NCH; ch++)
        s += *(const f32x4*)&ctxp[((size_t)ch * 64 + bh) * 4096 + flat];
    const float inv = stats[bh * 64 + d].y;
    __bf16* o = ctxT + (size_t)bh * 4096;
#pragma unroll
    for (int j = 0; j < 4; j++) o[(e0 + j) * 64 + d] = (__bf16)(s[j] * inv);
}

// ---------------------------------------------------------------------------
// pv_fused: per (bh, 256-col tile): q-softmax (unnormalized exp in LDS bf16)
// + MFMA 256x64 K=64 against ctxT, normalize in epilogue, write bf16 outT.
// ---------------------------------------------------------------------------
#define SPS 66   // LDS row stride (bf16)
__global__ __launch_bounds__(256) void pv_fused(__bf16* __restrict__ qkv,
                                                const __bf16* __restrict__ ctxT) {
    __shared__ __align__(16) __bf16 sp[256 * SPS];   // p rows [n][d]
    __shared__ __align__(16) __bf16 sctx[64 * SPS];  // ctxT rows [e][d]
    __shared__ float sinv[256];
    const int tileN = blockIdx.x;
    const int bh = blockIdx.y;
    const int b = bh >> 3, h = bh & 7;
    const int t = threadIdx.x;
    const int n0 = tileN * 256;
    const __bf16* qbase = qkv + (size_t)b * 1536 * L + (size_t)(h * 64) * L;

    {   // stage ctxT (64x64 bf16)
        const int e = t >> 2, c = t & 3;
        const bf16x8* src = (const bf16x8*)(ctxT + ((size_t)bh * 64 + e) * 64 + c * 16);
        *(bf16x8*)&sctx[e * SPS + c * 16] = src[0];
        *(bf16x8*)&sctx[e * SPS + c * 16 + 8] = src[1];
    }

    // read bf16 q column (coalesced across lanes), exp, sum, stage
    float m = -1e30f;
    float qv[64];
#pragma unroll
    for (int d = 0; d < 64; d++) {
        qv[d] = (float)qbase[(size_t)d * L + n0 + t];
        m = fmaxf(m, qv[d]);
    }
    float s = 0.f;
#pragma unroll
    for (int d0 = 0; d0 < 64; d0 += 8) {
        bf16x8 ek;
#pragma unroll
        for (int j = 0; j < 8; j++) {
            float e = __expf(qv[d0 + j] - m);
            s += e;
            ek[j] = (__bf16)e;
        }
        *(bf16x8*)&sp[t * SPS + d0] = ek;
    }
    sinv[t] = 1.0f / s;
    __syncthreads();

    // MFMA: out[n][e] = sum_d p[n][d] * ctxT[e][d]; 4 waves x 64 rows
    const int wave = t >> 6, lane = t & 63;
    const int wm = wave * 64;
    const int fr = lane & 15, kq = (lane >> 4) * 8;
    f32x4 acc[4][4];
#pragma unroll
    for (int i = 0; i < 4; i++)
#pragma unroll
        for (int j = 0; j < 4; j++) acc[i][j] = (f32x4)(0.0f);
#pragma unroll
    for (int kh = 0; kh < 2; kh++) {
        bf16x8 af[4], bfr[4];
#pragma unroll
        for (int i = 0; i < 4; i++)
            af[i] = *(const bf16x8*)&sp[(wm + i * 16 + fr) * SPS + kh * 32 + kq];
#pragma unroll
        for (int j = 0; j < 4; j++)
            bfr[j] = *(const bf16x8*)&sctx[(j * 16 + fr) * SPS + kh * 32 + kq];
#pragma unroll
        for (int i = 0; i < 4; i++)
#pragma unroll
            for (int j = 0; j < 4; j++)
                acc[i][j] = __builtin_amdgcn_mfma_f32_16x16x32_bf16(af[i], bfr[j], acc[i][j], 0, 0, 0);
    }

    // epilogue: normalize by 1/s[n], write bf16 outT[b][n][h*64+e]
    __bf16* ob = qkv + (size_t)b * 1536 * L + (size_t)512 * L;
    const int col = lane & 15, rbase = (lane >> 4) * 4;
#pragma unroll
    for (int i = 0; i < 4; i++) {
#pragma unroll
        for (int r = 0; r < 4; r++) {
            const int nl = wm + i * 16 + rbase + r;
            const float inv = sinv[nl];
            const size_t rowoff = (size_t)(n0 + nl) * 512 + h * 64;
#pragma unroll
            for (int j = 0; j < 4; j++)
                ob[rowoff + j * 16 + col] = (__bf16)(acc[i][j][r] * inv);
        }
    }
}

// ---------------------------------------------------------------------------
extern "C" void kernel_launch(void* const* d_in, const int* in_sizes, int n_in,
                              void* d_out, int out_size, void* d_ws, size_t ws_size,
                              hipStream_t stream) {
    const float* x    = (const float*)d_in[0];
    const float* Wqkv = (const float*)d_in[1];
    const float* Wout = (const float*)d_in[2];
    const float* bout = (const float*)d_in[3];
    float* y = (float*)d_out;

    __bf16* qkv   = (__bf16*)d_ws;                               // 8*1536*4096 bf16
    float*  ctxp  = (float*)(qkv + (size_t)8 * 1536 * L);        // NCH*64*4096 f32
    __bf16* xb    = (__bf16*)(ctxp + (size_t)NCH * 64 * 4096);   // 8*4096*512 bf16
    __bf16* Wqb   = xb + (size_t)8 * 4096 * 512;                 // 1536*512 bf16
    __bf16* Wob   = Wqb + (size_t)1536 * 512;                    // 512*512 bf16
    float2* stats = (float2*)(Wob + (size_t)512 * 512);          // 4096 float2
    __bf16* ctxT  = (__bf16*)(stats + 4096);                     // 64*4096 bf16

    const int convBlocks = (NX8 + NW18 + NW28 + 255) / 256;
    convert_all<<<dim3(convBlocks), 256, 0, stream>>>(x, Wqkv, Wout, xb);

    // qkv[b][o][l] = sum_d Wqkv[o][d] * x[b][l][d]   (M=1536, N=4096, K=512), bf16 out
    gemm_bf16_256<1536, 4096, 512, __bf16><<<dim3(4096 / 256, 1536 / 256, 8), 512, 0, stream>>>(
        Wqb, 0, xb, (size_t)4096 * 512, qkv, (size_t)1536 * 4096, nullptr);

    kstats<<<dim3(4096), 256, 0, stream>>>(qkv, stats);
    context_mfma<<<dim3(NCH, 64), 256, 0, stream>>>(qkv, stats, ctxp);
    ctx_reduce<<<dim3(256), 256, 0, stream>>>(ctxp, stats, ctxT);
    pv_fused<<<dim3(L / 256, 64), 256, 0, stream>>>(qkv, ctxT);

    // y[b][l][d] = sum_c outT[b][l][c] * Wout[d][c] + bout[d]  (M=4096, N=512, K=512), f32 out
    const __bf16* outT = qkv + (size_t)512 * L;
    gemm_bf16_256<4096, 512, 512, float><<<dim3(512 / 256, 4096 / 256, 8), 512, 0, stream>>>(
        outT, (size_t)1536 * L, Wob, 0, y, (size_t)4096 * 512, bout);
}

// Round 5
// 271.361 us; speedup vs baseline: 1.1016x; 1.1016x over previous
//
#include <hip/hip_runtime.h>

#define L 4096
#define D 512
#define NCH 16   // context n-chunks (256 n per chunk)

typedef __bf16 bf16x8 __attribute__((ext_vector_type(8)));
typedef float  f32x4  __attribute__((ext_vector_type(4)));

__device__ __forceinline__ void load_lds16(const void* g, void* l) {
    __builtin_amdgcn_global_load_lds(
        (const __attribute__((address_space(1))) void*)g,
        (__attribute__((address_space(3))) void*)l, 16, 0, 0);
}

__device__ __forceinline__ void barrier_mem() {
    asm volatile("" ::: "memory");
    __builtin_amdgcn_s_barrier();
    asm volatile("" ::: "memory");
}

// ---------------------------------------------------------------------------
// merged f32 -> bf16 conversion for x, Wqkv, Wout (contiguous dst regions)
// ---------------------------------------------------------------------------
#define NX8  (8 * 4096 * 512 / 8)
#define NW18 (1536 * 512 / 8)
#define NW28 (512 * 512 / 8)
__global__ __launch_bounds__(256) void convert_all(const float* __restrict__ x,
                                                   const float* __restrict__ Wq,
                                                   const float* __restrict__ Wo,
                                                   __bf16* __restrict__ dst) {
    int i = blockIdx.x * 256 + threadIdx.x;
    if (i >= NX8 + NW18 + NW28) return;
    const float* s;
    if (i < NX8)             s = x  + (size_t)i * 8;
    else if (i < NX8 + NW18) s = Wq + (size_t)(i - NX8) * 8;
    else                     s = Wo + (size_t)(i - NX8 - NW18) * 8;
    float4 a = ((const float4*)s)[0], b = ((const float4*)s)[1];
    bf16x8 o = {(__bf16)a.x, (__bf16)a.y, (__bf16)a.z, (__bf16)a.w,
                (__bf16)b.x, (__bf16)b.y, (__bf16)b.z, (__bf16)b.w};
    *(bf16x8*)(dst + (size_t)i * 8) = o;
}

// ---------------------------------------------------------------------------
// 256x256-tile TN bf16 MFMA GEMM, deep-pipelined K-half ring.
// C[b][m][n] = sum_k A[b][m][k] * B[b][n][k] (+bias[n]). 512 thr = 8 waves 2Mx4N.
// Unit = one operand, one K-half: 256 rows x 32 k cols (16 KB, 2 load_lds/thr).
// 4-slot LDS ring per operand, slot(q) = q&3 (q = K-half index, NQ = K/32).
// Units for K-half q staged during pair q-3 -> consumed ~3 pairs after issue.
// Pair q body: {vmcnt(counted); barrier; stage B(q+3); 12x ds_read_b128
//   (bfr, a0, a1); stage A(q+3); lgkm(4); 16 MFMA (a0xbfr); lgkm(0);
//   16 MFMA (a1xbfr)} -- 1 barrier + 1 counted vmcnt + 1 counted lgkm per pair.
// Hazards: slot-q reads complete before each wave's pair-q lgkm(0); barrier
// at pair q+1 orders them before the stage of slot (q+4)&3 == q&3.
// vmcnt ladder: prologue 12 outstanding; steady vmcnt(8); tail 4 -> 0.
// Swizzle (64B rows): slot (row,cc) holds k-chunk cc^((row>>1)&3); read
// chunk g^((row>>1)&3). Each 8-row group covers all 32 banks exactly once;
// two groups -> 2-way aliasing (free per m136).
// ---------------------------------------------------------------------------
template <int M, int N, int K, typename CT>
__global__ __launch_bounds__(512, 2) void gemm_bf16_256(
    const __bf16* __restrict__ A, size_t aStride,
    const __bf16* __restrict__ B, size_t bStride,
    CT* __restrict__ C, size_t cStride,
    const float* __restrict__ bias) {
    __shared__ __align__(16) __bf16 sA[4][256 * 32];
    __shared__ __align__(16) __bf16 sB[4][256 * 32];
    constexpr int NQ = K / 32;
    const int b  = blockIdx.z;
    const int m0 = blockIdx.y * 256;
    const int n0 = blockIdx.x * 256;
    const int t    = threadIdx.x;
    const int wave = t >> 6, lane = t & 63;
    const int wm = (wave >> 2) * 128;   // wave M-offset
    const int wn = (wave & 3) * 64;     // wave N-offset
    const int fr = lane & 15, g = lane >> 4;
    const __bf16* Ab = A + (size_t)b * aStride + (size_t)m0 * K;
    const __bf16* Bb = B + (size_t)b * bStride + (size_t)n0 * K;
    CT* Cb = C + (size_t)b * cStride;

    f32x4 acc[8][4];
#pragma unroll
    for (int i = 0; i < 8; i++)
#pragma unroll
        for (int j = 0; j < 4; j++) acc[i][j] = (f32x4)(0.0f);

    // stage one unit (16 KB): 2 x global_load_lds per thread, lane-linear dest
    auto stageU = [&](const __bf16* Pb, int q, __bf16* slot) {
#pragma unroll
        for (int it = 0; it < 2; ++it) {
            const int gi = it * 512 + t;          // 16B granule 0..1023
            const int row = gi >> 2, cc = gi & 3;
            const int scc = cc ^ ((row >> 1) & 3);
            load_lds16(Pb + (size_t)row * K + q * 32 + scc * 8, slot + gi * 8);
        }
    };
    auto rdFrag = [&](const __bf16* slot, int rowbase) -> bf16x8 {
        const int row = rowbase + fr;
        return *(const bf16x8*)&slot[row * 32 + ((g ^ ((row >> 1) & 3)) * 8)];
    };

    // prologue: units for K-halves 0,1,2 (12 outstanding loads)
    stageU(Bb, 0, sB[0]); stageU(Ab, 0, sA[0]);
    stageU(Bb, 1, sB[1]); stageU(Ab, 1, sA[1]);
    stageU(Bb, 2, sB[2]); stageU(Ab, 2, sA[2]);

    for (int q = 0; q < NQ; ++q) {
        const int sl = q & 3;
        const __bf16* sAq = sA[sl];
        const __bf16* sBq = sB[sl];
        if (q <= NQ - 3)      asm volatile("s_waitcnt vmcnt(8)" ::: "memory");
        else if (q == NQ - 2) asm volatile("s_waitcnt vmcnt(4)" ::: "memory");
        else                  asm volatile("s_waitcnt vmcnt(0)" ::: "memory");
        barrier_mem();                         // units A(q),B(q) visible to all
        if (q + 3 < NQ) stageU(Bb, q + 3, sB[(q + 3) & 3]);
        bf16x8 bfr[4], a0[4], a1[4];
#pragma unroll
        for (int j = 0; j < 4; ++j) bfr[j] = rdFrag(sBq, wn + j * 16);
#pragma unroll
        for (int i = 0; i < 4; ++i) a0[i] = rdFrag(sAq, wm + i * 16);
#pragma unroll
        for (int i = 0; i < 4; ++i) a1[i] = rdFrag(sAq, wm + 64 + i * 16);
        if (q + 3 < NQ) stageU(Ab, q + 3, sA[(q + 3) & 3]);
        asm volatile("s_waitcnt lgkmcnt(4)" ::: "memory");   // bfr + a0 ready
        __builtin_amdgcn_sched_barrier(0);
        __builtin_amdgcn_s_setprio(1);
#pragma unroll
        for (int i = 0; i < 4; ++i)
#pragma unroll
            for (int j = 0; j < 4; ++j)
                acc[i][j] = __builtin_amdgcn_mfma_f32_16x16x32_bf16(a0[i], bfr[j], acc[i][j], 0, 0, 0);
        __builtin_amdgcn_s_setprio(0);
        asm volatile("s_waitcnt lgkmcnt(0)" ::: "memory");   // a1 ready
        __builtin_amdgcn_sched_barrier(0);
        __builtin_amdgcn_s_setprio(1);
#pragma unroll
        for (int i = 0; i < 4; ++i)
#pragma unroll
            for (int j = 0; j < 4; ++j)
                acc[4 + i][j] = __builtin_amdgcn_mfma_f32_16x16x32_bf16(a1[i], bfr[j], acc[4 + i][j], 0, 0, 0);
        __builtin_amdgcn_s_setprio(0);
    }

    // epilogue: j-innermost so adjacent 32B chunks issue back-to-back
    const int rb = g * 4;
    float bv[4];
#pragma unroll
    for (int j = 0; j < 4; ++j) bv[j] = bias ? bias[n0 + wn + j * 16 + fr] : 0.0f;
#pragma unroll
    for (int i = 0; i < 8; ++i) {
#pragma unroll
        for (int r = 0; r < 4; ++r) {
            const int m = m0 + wm + i * 16 + rb + r;
            CT* rowp = Cb + (size_t)m * N + n0 + wn + fr;
#pragma unroll
            for (int j = 0; j < 4; ++j)
                rowp[j * 16] = (CT)(acc[i][j][r] + bv[j]);
        }
    }
}

// ---------------------------------------------------------------------------
// k-row stats over bf16 k rows: per row compute (max, 1/sumexp). grid 4096.
// ---------------------------------------------------------------------------
__global__ __launch_bounds__(256) void kstats(const __bf16* __restrict__ qkv,
                                              float2* __restrict__ stats) {
    const int r = blockIdx.x;
    const int b = r >> 9, hc = r & 511;
    const __bf16* row = qkv + (size_t)b * 1536 * L + (size_t)(512 + hc) * L;
    __shared__ float sred[4];
    const int t = threadIdx.x;
    const bf16x8* p = (const bf16x8*)row;
    bf16x8 c0 = p[t * 2], c1 = p[t * 2 + 1];
    float v[16];
    float m = -1e30f;
#pragma unroll
    for (int j = 0; j < 8; j++) {
        v[j] = (float)c0[j];
        v[8 + j] = (float)c1[j];
    }
#pragma unroll
    for (int j = 0; j < 16; j++) m = fmaxf(m, v[j]);
#pragma unroll
    for (int off = 32; off > 0; off >>= 1) m = fmaxf(m, __shfl_down(m, off, 64));
    if ((t & 63) == 0) sred[t >> 6] = m;
    __syncthreads();
    const float m4 = fmaxf(fmaxf(sred[0], sred[1]), fmaxf(sred[2], sred[3]));
    float s = 0.f;
#pragma unroll
    for (int j = 0; j < 16; j++) s += __expf(v[j] - m4);
#pragma unroll
    for (int off = 32; off > 0; off >>= 1) s += __shfl_down(s, off, 64);
    __syncthreads();
    if ((t & 63) == 0) sred[t >> 6] = s;
    __syncthreads();
    if (t == 0) {
        const float stot = sred[0] + sred[1] + sred[2] + sred[3];
        stats[r] = make_float2(m4, 1.0f / stot);
    }
}

// ---------------------------------------------------------------------------
// MFMA context partials: ctxp[chunk][bh][d][e] (f32, d-major) =
//   sum_{n in chunk} exp(k[d,n]-m_d) * v[e,n]   (un-normalized; 1/s at reduce)
// grid (NCH, 64 bh), block 256. Each of 4 waves takes a 64-n K-slice.
// ---------------------------------------------------------------------------
#define SKS 264   // LDS bf16 row stride (256 data + 8 pad)
__global__ __launch_bounds__(256) void context_mfma(const __bf16* __restrict__ qkv,
                                                    const float2* __restrict__ stats,
                                                    float* __restrict__ ctxp) {
    __shared__ __align__(16) __bf16 smem[2 * 64 * SKS];  // 67.6 KB; reused as f32 red[4][4096]
    __shared__ float smax[64];
    __bf16* sk = smem;
    __bf16* sv = smem + 64 * SKS;
    const int chunk = blockIdx.x;
    const int bh = blockIdx.y;
    const int b = bh >> 3, h = bh & 7;
    const __bf16* kbase = qkv + (size_t)b * 1536 * L + (size_t)(512 + h * 64) * L;
    const __bf16* vbase = qkv + (size_t)b * 1536 * L + (size_t)(1024 + h * 64) * L;
    const int t = threadIdx.x;
    if (t < 64) smax[t] = stats[bh * 64 + t].x;
    __syncthreads();

    // stage: thread t -> row d = t>>2, n-quarter (t&3)*64
    {
        const int d = t >> 2, noff = (t & 3) * 64;
        const int n0 = chunk * 256;
        const __bf16* kp = kbase + (size_t)d * L + n0 + noff;
        const __bf16* vp = vbase + (size_t)d * L + n0 + noff;
        const float md = smax[d];
#pragma unroll
        for (int c = 0; c < 8; c++) {
            bf16x8 kk = *(const bf16x8*)(kp + c * 8);
            bf16x8 vv = *(const bf16x8*)(vp + c * 8);
            bf16x8 ek;
#pragma unroll
            for (int j = 0; j < 8; j++) ek[j] = (__bf16)__expf((float)kk[j] - md);
            *(bf16x8*)&sk[d * SKS + noff + c * 8] = ek;
            *(bf16x8*)&sv[d * SKS + noff + c * 8] = vv;
        }
    }
    __syncthreads();

    // MFMA: wave w covers n in [w*64, w*64+64)
    const int wave = t >> 6, lane = t & 63;
    const int fr = lane & 15, kq = (lane >> 4) * 8;
    f32x4 acc[4][4];
#pragma unroll
    for (int i = 0; i < 4; i++)
#pragma unroll
        for (int j = 0; j < 4; j++) acc[i][j] = (f32x4)(0.0f);
#pragma unroll
    for (int kh = 0; kh < 2; kh++) {
        const int koff = wave * 64 + kh * 32 + kq;
        bf16x8 af[4], bfr[4];
#pragma unroll
        for (int i = 0; i < 4; i++) {
            af[i]  = *(const bf16x8*)&sk[(i * 16 + fr) * SKS + koff];
            bfr[i] = *(const bf16x8*)&sv[(i * 16 + fr) * SKS + koff];
        }
#pragma unroll
        for (int i = 0; i < 4; i++)
#pragma unroll
            for (int j = 0; j < 4; j++)
                acc[i][j] = __builtin_amdgcn_mfma_f32_16x16x32_bf16(af[i], bfr[j], acc[i][j], 0, 0, 0);
    }
    __syncthreads();   // MFMA LDS reads done; safe to overwrite smem

    // cross-wave reduce via LDS: red[w][d*64+e] (d = A rows, e = B rows)
    float* red = (float*)smem;   // 4 * 4096 f32 = 64 KB
    const int col = lane & 15, rbase = (lane >> 4) * 4;
#pragma unroll
    for (int i = 0; i < 4; i++)
#pragma unroll
        for (int j = 0; j < 4; j++)
#pragma unroll
            for (int r = 0; r < 4; r++) {
                const int dd = i * 16 + rbase + r;
                const int ee = j * 16 + col;
                red[wave * 4096 + dd * 64 + ee] = acc[i][j][r];
            }
    __syncthreads();
    float* cp = ctxp + ((size_t)chunk * 64 + bh) * 4096;
#pragma unroll
    for (int gg = 0; gg < 4; gg++) {
        const int idx = t * 16 + gg * 4;
        f32x4 s = *(const f32x4*)&red[idx];
        s += *(const f32x4*)&red[4096 + idx];
        s += *(const f32x4*)&red[8192 + idx];
        s += *(const f32x4*)&red[12288 + idx];
        *(f32x4*)&cp[idx] = s;
    }
}

// ---------------------------------------------------------------------------
// reduce ctx partials over chunks, apply 1/s_d, transpose [d][e]->[e][d],
// emit bf16 ctxT[bh][e][d]. grid 256.
// ---------------------------------------------------------------------------
__global__ __launch_bounds__(256) void ctx_reduce(const float* __restrict__ ctxp,
                                                  const float2* __restrict__ stats,
                                                  __bf16* __restrict__ ctxT) {
    const int bh = blockIdx.x >> 2, quarter = blockIdx.x & 3;
    const int t = threadIdx.x;
    const int flat = quarter * 1024 + t * 4;   // d-major: d = flat>>6, e0 = flat&63
    const int d = flat >> 6, e0 = flat & 63;
    f32x4 s = (f32x4)(0.0f);
    for (int ch = 0; ch < NCH; ch++)
        s += *(const f32x4*)&ctxp[((size_t)ch * 64 + bh) * 4096 + flat];
    const float inv = stats[bh * 64 + d].y;
    __bf16* o = ctxT + (size_t)bh * 4096;
#pragma unroll
    for (int j = 0; j < 4; j++) o[(e0 + j) * 64 + d] = (__bf16)(s[j] * inv);
}

// ---------------------------------------------------------------------------
// pv_fused: per (bh, 256-col tile): q-softmax (unnormalized exp in LDS bf16)
// + MFMA 256x64 K=64 against ctxT, normalize in epilogue, write bf16 outT.
// ---------------------------------------------------------------------------
#define SPS 66   // LDS row stride (bf16)
__global__ __launch_bounds__(256) void pv_fused(__bf16* __restrict__ qkv,
                                                const __bf16* __restrict__ ctxT) {
    __shared__ __align__(16) __bf16 sp[256 * SPS];   // p rows [n][d]
    __shared__ __align__(16) __bf16 sctx[64 * SPS];  // ctxT rows [e][d]
    __shared__ float sinv[256];
    const int tileN = blockIdx.x;
    const int bh = blockIdx.y;
    const int b = bh >> 3, h = bh & 7;
    const int t = threadIdx.x;
    const int n0 = tileN * 256;
    const __bf16* qbase = qkv + (size_t)b * 1536 * L + (size_t)(h * 64) * L;

    {   // stage ctxT (64x64 bf16)
        const int e = t >> 2, c = t & 3;
        const bf16x8* src = (const bf16x8*)(ctxT + ((size_t)bh * 64 + e) * 64 + c * 16);
        *(bf16x8*)&sctx[e * SPS + c * 16] = src[0];
        *(bf16x8*)&sctx[e * SPS + c * 16 + 8] = src[1];
    }

    // read bf16 q column (coalesced across lanes), exp, sum, stage
    float m = -1e30f;
    float qv[64];
#pragma unroll
    for (int d = 0; d < 64; d++) {
        qv[d] = (float)qbase[(size_t)d * L + n0 + t];
        m = fmaxf(m, qv[d]);
    }
    float s = 0.f;
#pragma unroll
    for (int d0 = 0; d0 < 64; d0 += 8) {
        bf16x8 ek;
#pragma unroll
        for (int j = 0; j < 8; j++) {
            float e = __expf(qv[d0 + j] - m);
            s += e;
            ek[j] = (__bf16)e;
        }
        *(bf16x8*)&sp[t * SPS + d0] = ek;
    }
    sinv[t] = 1.0f / s;
    __syncthreads();

    // MFMA: out[n][e] = sum_d p[n][d] * ctxT[e][d]; 4 waves x 64 rows
    const int wave = t >> 6, lane = t & 63;
    const int wm = wave * 64;
    const int fr = lane & 15, kq = (lane >> 4) * 8;
    f32x4 acc[4][4];
#pragma unroll
    for (int i = 0; i < 4; i++)
#pragma unroll
        for (int j = 0; j < 4; j++) acc[i][j] = (f32x4)(0.0f);
#pragma unroll
    for (int kh = 0; kh < 2; kh++) {
        bf16x8 af[4], bfr[4];
#pragma unroll
        for (int i = 0; i < 4; i++)
            af[i] = *(const bf16x8*)&sp[(wm + i * 16 + fr) * SPS + kh * 32 + kq];
#pragma unroll
        for (int j = 0; j < 4; j++)
            bfr[j] = *(const bf16x8*)&sctx[(j * 16 + fr) * SPS + kh * 32 + kq];
#pragma unroll
        for (int i = 0; i < 4; i++)
#pragma unroll
            for (int j = 0; j < 4; j++)
                acc[i][j] = __builtin_amdgcn_mfma_f32_16x16x32_bf16(af[i], bfr[j], acc[i][j], 0, 0, 0);
    }

    // epilogue: normalize by 1/s[n], write bf16 outT[b][n][h*64+e]
    __bf16* ob = qkv + (size_t)b * 1536 * L + (size_t)512 * L;
    const int col = lane & 15, rbase = (lane >> 4) * 4;
#pragma unroll
    for (int i = 0; i < 4; i++) {
#pragma unroll
        for (int r = 0; r < 4; r++) {
            const int nl = wm + i * 16 + rbase + r;
            const float inv = sinv[nl];
            const size_t rowoff = (size_t)(n0 + nl) * 512 + h * 64;
#pragma unroll
            for (int j = 0; j < 4; j++)
                ob[rowoff + j * 16 + col] = (__bf16)(acc[i][j][r] * inv);
        }
    }
}

// ---------------------------------------------------------------------------
extern "C" void kernel_launch(void* const* d_in, const int* in_sizes, int n_in,
                              void* d_out, int out_size, void* d_ws, size_t ws_size,
                              hipStream_t stream) {
    const float* x    = (const float*)d_in[0];
    const float* Wqkv = (const float*)d_in[1];
    const float* Wout = (const float*)d_in[2];
    const float* bout = (const float*)d_in[3];
    float* y = (float*)d_out;

    __bf16* qkv   = (__bf16*)d_ws;                               // 8*1536*4096 bf16
    float*  ctxp  = (float*)(qkv + (size_t)8 * 1536 * L);        // NCH*64*4096 f32
    __bf16* xb    = (__bf16*)(ctxp + (size_t)NCH * 64 * 4096);   // 8*4096*512 bf16
    __bf16* Wqb   = xb + (size_t)8 * 4096 * 512;                 // 1536*512 bf16
    __bf16* Wob   = Wqb + (size_t)1536 * 512;                    // 512*512 bf16
    float2* stats = (float2*)(Wob + (size_t)512 * 512);          // 4096 float2
    __bf16* ctxT  = (__bf16*)(stats + 4096);                     // 64*4096 bf16

    const int convBlocks = (NX8 + NW18 + NW28 + 255) / 256;
    convert_all<<<dim3(convBlocks), 256, 0, stream>>>(x, Wqkv, Wout, xb);

    // qkv[b][o][l] = sum_d Wqkv[o][d] * x[b][l][d]   (M=1536, N=4096, K=512), bf16 out
    gemm_bf16_256<1536, 4096, 512, __bf16><<<dim3(4096 / 256, 1536 / 256, 8), 512, 0, stream>>>(
        Wqb, 0, xb, (size_t)4096 * 512, qkv, (size_t)1536 * 4096, nullptr);

    kstats<<<dim3(4096), 256, 0, stream>>>(qkv, stats);
    context_mfma<<<dim3(NCH, 64), 256, 0, stream>>>(qkv, stats, ctxp);
    ctx_reduce<<<dim3(256), 256, 0, stream>>>(ctxp, stats, ctxT);
    pv_fused<<<dim3(L / 256, 64), 256, 0, stream>>>(qkv, ctxT);

    // y[b][l][d] = sum_c outT[b][l][c] * Wout[d][c] + bout[d]  (M=4096, N=512, K=512), f32 out
    const __bf16* outT = qkv + (size_t)512 * L;
    gemm_bf16_256<4096, 512, 512, float><<<dim3(512 / 256, 4096 / 256, 8), 512, 0, stream>>>(
        outT, (size_t)1536 * L, Wob, 0, y, (size_t)4096 * 512, bout);
}

// Round 6
// 264.296 us; speedup vs baseline: 1.1311x; 1.0267x over previous
//
#include <hip/hip_runtime.h>

#define L 4096
#define D 512
#define NCH 16   // context n-chunks (256 n per chunk)

typedef __bf16 bf16x8 __attribute__((ext_vector_type(8)));
typedef float  f32x4  __attribute__((ext_vector_type(4)));

__device__ __forceinline__ void load_lds16(const void* g, void* l) {
    __builtin_amdgcn_global_load_lds(
        (const __attribute__((address_space(1))) void*)g,
        (__attribute__((address_space(3))) void*)l, 16, 0, 0);
}

__device__ __forceinline__ void barrier_mem() {
    asm volatile("" ::: "memory");
    __builtin_amdgcn_s_barrier();
    asm volatile("" ::: "memory");
}

// ---------------------------------------------------------------------------
// merged f32 -> bf16 conversion for x, Wqkv, Wout (contiguous dst regions)
// ---------------------------------------------------------------------------
#define NX8  (8 * 4096 * 512 / 8)
#define NW18 (1536 * 512 / 8)
#define NW28 (512 * 512 / 8)
__global__ __launch_bounds__(256) void convert_all(const float* __restrict__ x,
                                                   const float* __restrict__ Wq,
                                                   const float* __restrict__ Wo,
                                                   __bf16* __restrict__ dst) {
    int i = blockIdx.x * 256 + threadIdx.x;
    if (i >= NX8 + NW18 + NW28) return;
    const float* s;
    if (i < NX8)             s = x  + (size_t)i * 8;
    else if (i < NX8 + NW18) s = Wq + (size_t)(i - NX8) * 8;
    else                     s = Wo + (size_t)(i - NX8 - NW18) * 8;
    float4 a = ((const float4*)s)[0], b = ((const float4*)s)[1];
    bf16x8 o = {(__bf16)a.x, (__bf16)a.y, (__bf16)a.z, (__bf16)a.w,
                (__bf16)b.x, (__bf16)b.y, (__bf16)b.z, (__bf16)b.w};
    *(bf16x8*)(dst + (size_t)i * 8) = o;
}

// ---------------------------------------------------------------------------
// 256x256-tile TN bf16 MFMA GEMM, K-half ring + cross-pair REGISTER prefetch.
// C[b][m][n] = sum_k A[b][m][k] * B[b][n][k] (+bias[n]). 512 thr = 8 waves 2Mx4N.
// Unit = one operand, one K-half: 256 rows x 32 k (16 KB). 4-slot ring/operand.
// Pair q body: {vmcnt(8 counted); barrier; stage units q+3 (8 gload_lds);
//   lgkm(0) [drains PREV pair's prefetch reads -> cur frags resident];
//   issue 12 ds_read -> nxt frags (slot (q+1)&3, staged & barrier-proven);
//   32 MFMA on cur frags (zero LDS wait -> LDS pipe overlaps matrix pipe)}.
// Hazards: vmcnt(8)@q retires units q+1 per-wave; barrier@q makes it all-wave
//   -> slot (q+1)&3 readable post-barrier. Prefetch reads of slot s drain at
//   lgkm(0)@pair s (before barrier@s+1); re-stage of that slot is post-
//   barrier@s+1 -> no WAR. Stage@q writes slot (q+3)&3 != (q+1)&3 being read.
// vmcnt ladder: prologue 24 out -> vmcnt(16) (units 0 done); steady vmcnt(8);
//   tail q>NQ-3 -> vmcnt(0). Frag double-buffer is STATIC (two named arrays,
//   bodies alternated) per rule 20.
// Swizzle (64B rows): slot (row,cc) holds k-chunk cc^((row>>1)&3); read chunk
//   g^((row>>1)&3) -> 2-way bank aliasing max (free per m136).
// ---------------------------------------------------------------------------
template <int M, int N, int K, typename CT>
__global__ __launch_bounds__(512, 2) void gemm_bf16_256(
    const __bf16* __restrict__ A, size_t aStride,
    const __bf16* __restrict__ B, size_t bStride,
    CT* __restrict__ C, size_t cStride,
    const float* __restrict__ bias) {
    __shared__ __align__(16) __bf16 sA[4][256 * 32];
    __shared__ __align__(16) __bf16 sB[4][256 * 32];
    constexpr int NQ = K / 32;
    const int b  = blockIdx.z;
    const int m0 = blockIdx.y * 256;
    const int n0 = blockIdx.x * 256;
    const int t    = threadIdx.x;
    const int wave = t >> 6, lane = t & 63;
    const int wm = (wave >> 2) * 128;   // wave M-offset
    const int wn = (wave & 3) * 64;     // wave N-offset
    const int fr = lane & 15, g = lane >> 4;
    const __bf16* Ab = A + (size_t)b * aStride + (size_t)m0 * K;
    const __bf16* Bb = B + (size_t)b * bStride + (size_t)n0 * K;
    CT* Cb = C + (size_t)b * cStride;

    f32x4 acc[8][4];
#pragma unroll
    for (int i = 0; i < 8; i++)
#pragma unroll
        for (int j = 0; j < 4; j++) acc[i][j] = (f32x4)(0.0f);

    // stage one unit (16 KB): 2 x global_load_lds per thread, lane-linear dest
    auto stageU = [&](const __bf16* Pb, int q, __bf16* slot) {
#pragma unroll
        for (int it = 0; it < 2; ++it) {
            const int gi = it * 512 + t;          // 16B granule 0..1023
            const int row = gi >> 2, cc = gi & 3;
            const int scc = cc ^ ((row >> 1) & 3);
            load_lds16(Pb + (size_t)row * K + q * 32 + scc * 8, slot + gi * 8);
        }
    };
    auto rdFrag = [&](const __bf16* slot, int rowbase) -> bf16x8 {
        const int row = rowbase + fr;
        return *(const bf16x8*)&slot[row * 32 + ((g ^ ((row >> 1) & 3)) * 8)];
    };
    auto readFrags = [&](int sl, bf16x8* fB, bf16x8* fA) {
        const __bf16* sBq = sB[sl];
        const __bf16* sAq = sA[sl];
#pragma unroll
        for (int j = 0; j < 4; ++j) fB[j] = rdFrag(sBq, wn + j * 16);
#pragma unroll
        for (int i = 0; i < 8; ++i) fA[i] = rdFrag(sAq, wm + i * 16);
    };
    auto mfmaAll = [&](const bf16x8* fB, const bf16x8* fA) {
        __builtin_amdgcn_s_setprio(1);
#pragma unroll
        for (int i = 0; i < 8; ++i)
#pragma unroll
            for (int j = 0; j < 4; ++j)
                acc[i][j] = __builtin_amdgcn_mfma_f32_16x16x32_bf16(
                    fA[i], fB[j], acc[i][j], 0, 0, 0);
        __builtin_amdgcn_s_setprio(0);
    };
    auto body = [&](int q, bf16x8* curB, bf16x8* curA, bf16x8* nxtB, bf16x8* nxtA) {
        if (q <= NQ - 3) asm volatile("s_waitcnt vmcnt(8)" ::: "memory");
        else             asm volatile("s_waitcnt vmcnt(0)" ::: "memory");
        barrier_mem();                          // units q, q+1 staged (all waves)
        if (q + 3 < NQ) {
            stageU(Bb, q + 3, sB[(q + 3) & 3]);
            stageU(Ab, q + 3, sA[(q + 3) & 3]);
        }
        asm volatile("s_waitcnt lgkmcnt(0)" ::: "memory");   // cur frags resident
        __builtin_amdgcn_sched_barrier(0);
        if (q + 1 < NQ) readFrags((q + 1) & 3, nxtB, nxtA);  // prefetch next pair
        __builtin_amdgcn_sched_barrier(0);
        mfmaAll(curB, curA);                    // LDS reads retire under MFMA
    };

    // prologue: units 0,1,2 (24 loads); wait units 0; read pair-0 frags
    stageU(Bb, 0, sB[0]); stageU(Ab, 0, sA[0]);
    stageU(Bb, 1, sB[1]); stageU(Ab, 1, sA[1]);
    stageU(Bb, 2, sB[2]); stageU(Ab, 2, sA[2]);
    asm volatile("s_waitcnt vmcnt(16)" ::: "memory");
    barrier_mem();
    bf16x8 fB0[4], fA0[8], fB1[4], fA1[8];
    readFrags(0, fB0, fA0);

    for (int q2 = 0; q2 < NQ; q2 += 2) {
        body(q2,     fB0, fA0, fB1, fA1);
        body(q2 + 1, fB1, fA1, fB0, fA0);
    }

    // epilogue: j-innermost so adjacent 32B chunks issue back-to-back
    const int rb = g * 4;
    float bv[4];
#pragma unroll
    for (int j = 0; j < 4; ++j) bv[j] = bias ? bias[n0 + wn + j * 16 + fr] : 0.0f;
#pragma unroll
    for (int i = 0; i < 8; ++i) {
#pragma unroll
        for (int r = 0; r < 4; ++r) {
            const int m = m0 + wm + i * 16 + rb + r;
            CT* rowp = Cb + (size_t)m * N + n0 + wn + fr;
#pragma unroll
            for (int j = 0; j < 4; ++j)
                rowp[j * 16] = (CT)(acc[i][j][r] + bv[j]);
        }
    }
}

// ---------------------------------------------------------------------------
// k-row stats over bf16 k rows: per row compute (max, 1/sumexp). grid 4096.
// ---------------------------------------------------------------------------
__global__ __launch_bounds__(256) void kstats(const __bf16* __restrict__ qkv,
                                              float2* __restrict__ stats) {
    const int r = blockIdx.x;
    const int b = r >> 9, hc = r & 511;
    const __bf16* row = qkv + (size_t)b * 1536 * L + (size_t)(512 + hc) * L;
    __shared__ float sred[4];
    const int t = threadIdx.x;
    const bf16x8* p = (const bf16x8*)row;
    bf16x8 c0 = p[t * 2], c1 = p[t * 2 + 1];
    float v[16];
    float m = -1e30f;
#pragma unroll
    for (int j = 0; j < 8; j++) {
        v[j] = (float)c0[j];
        v[8 + j] = (float)c1[j];
    }
#pragma unroll
    for (int j = 0; j < 16; j++) m = fmaxf(m, v[j]);
#pragma unroll
    for (int off = 32; off > 0; off >>= 1) m = fmaxf(m, __shfl_down(m, off, 64));
    if ((t & 63) == 0) sred[t >> 6] = m;
    __syncthreads();
    const float m4 = fmaxf(fmaxf(sred[0], sred[1]), fmaxf(sred[2], sred[3]));
    float s = 0.f;
#pragma unroll
    for (int j = 0; j < 16; j++) s += __expf(v[j] - m4);
#pragma unroll
    for (int off = 32; off > 0; off >>= 1) s += __shfl_down(s, off, 64);
    __syncthreads();
    if ((t & 63) == 0) sred[t >> 6] = s;
    __syncthreads();
    if (t == 0) {
        const float stot = sred[0] + sred[1] + sred[2] + sred[3];
        stats[r] = make_float2(m4, 1.0f / stot);
    }
}

// ---------------------------------------------------------------------------
// MFMA context partials: ctxp[chunk][bh][d][e] (f32, d-major) =
//   sum_{n in chunk} exp(k[d,n]-m_d) * v[e,n]   (un-normalized; 1/s at reduce)
// grid (NCH, 64 bh), block 256. Each of 4 waves takes a 64-n K-slice.
// ---------------------------------------------------------------------------
#define SKS 264   // LDS bf16 row stride (256 data + 8 pad)
__global__ __launch_bounds__(256) void context_mfma(const __bf16* __restrict__ qkv,
                                                    const float2* __restrict__ stats,
                                                    float* __restrict__ ctxp) {
    __shared__ __align__(16) __bf16 smem[2 * 64 * SKS];  // 67.6 KB; reused as f32 red[4][4096]
    __shared__ float smax[64];
    __bf16* sk = smem;
    __bf16* sv = smem + 64 * SKS;
    const int chunk = blockIdx.x;
    const int bh = blockIdx.y;
    const int b = bh >> 3, h = bh & 7;
    const __bf16* kbase = qkv + (size_t)b * 1536 * L + (size_t)(512 + h * 64) * L;
    const __bf16* vbase = qkv + (size_t)b * 1536 * L + (size_t)(1024 + h * 64) * L;
    const int t = threadIdx.x;
    if (t < 64) smax[t] = stats[bh * 64 + t].x;
    __syncthreads();

    // stage: thread t -> row d = t>>2, n-quarter (t&3)*64
    {
        const int d = t >> 2, noff = (t & 3) * 64;
        const int n0 = chunk * 256;
        const __bf16* kp = kbase + (size_t)d * L + n0 + noff;
        const __bf16* vp = vbase + (size_t)d * L + n0 + noff;
        const float md = smax[d];
#pragma unroll
        for (int c = 0; c < 8; c++) {
            bf16x8 kk = *(const bf16x8*)(kp + c * 8);
            bf16x8 vv = *(const bf16x8*)(vp + c * 8);
            bf16x8 ek;
#pragma unroll
            for (int j = 0; j < 8; j++) ek[j] = (__bf16)__expf((float)kk[j] - md);
            *(bf16x8*)&sk[d * SKS + noff + c * 8] = ek;
            *(bf16x8*)&sv[d * SKS + noff + c * 8] = vv;
        }
    }
    __syncthreads();

    // MFMA: wave w covers n in [w*64, w*64+64)
    const int wave = t >> 6, lane = t & 63;
    const int fr = lane & 15, kq = (lane >> 4) * 8;
    f32x4 acc[4][4];
#pragma unroll
    for (int i = 0; i < 4; i++)
#pragma unroll
        for (int j = 0; j < 4; j++) acc[i][j] = (f32x4)(0.0f);
#pragma unroll
    for (int kh = 0; kh < 2; kh++) {
        const int koff = wave * 64 + kh * 32 + kq;
        bf16x8 af[4], bfr[4];
#pragma unroll
        for (int i = 0; i < 4; i++) {
            af[i]  = *(const bf16x8*)&sk[(i * 16 + fr) * SKS + koff];
            bfr[i] = *(const bf16x8*)&sv[(i * 16 + fr) * SKS + koff];
        }
#pragma unroll
        for (int i = 0; i < 4; i++)
#pragma unroll
            for (int j = 0; j < 4; j++)
                acc[i][j] = __builtin_amdgcn_mfma_f32_16x16x32_bf16(af[i], bfr[j], acc[i][j], 0, 0, 0);
    }
    __syncthreads();   // MFMA LDS reads done; safe to overwrite smem

    // cross-wave reduce via LDS: red[w][d*64+e] (d = A rows, e = B rows)
    float* red = (float*)smem;   // 4 * 4096 f32 = 64 KB
    const int col = lane & 15, rbase = (lane >> 4) * 4;
#pragma unroll
    for (int i = 0; i < 4; i++)
#pragma unroll
        for (int j = 0; j < 4; j++)
#pragma unroll
            for (int r = 0; r < 4; r++) {
                const int dd = i * 16 + rbase + r;
                const int ee = j * 16 + col;
                red[wave * 4096 + dd * 64 + ee] = acc[i][j][r];
            }
    __syncthreads();
    float* cp = ctxp + ((size_t)chunk * 64 + bh) * 4096;
#pragma unroll
    for (int gg = 0; gg < 4; gg++) {
        const int idx = t * 16 + gg * 4;
        f32x4 s = *(const f32x4*)&red[idx];
        s += *(const f32x4*)&red[4096 + idx];
        s += *(const f32x4*)&red[8192 + idx];
        s += *(const f32x4*)&red[12288 + idx];
        *(f32x4*)&cp[idx] = s;
    }
}

// ---------------------------------------------------------------------------
// reduce ctx partials over chunks, apply 1/s_d, transpose [d][e]->[e][d],
// emit bf16 ctxT[bh][e][d]. grid 256.
// ---------------------------------------------------------------------------
__global__ __launch_bounds__(256) void ctx_reduce(const float* __restrict__ ctxp,
                                                  const float2* __restrict__ stats,
                                                  __bf16* __restrict__ ctxT) {
    const int bh = blockIdx.x >> 2, quarter = blockIdx.x & 3;
    const int t = threadIdx.x;
    const int flat = quarter * 1024 + t * 4;   // d-major: d = flat>>6, e0 = flat&63
    const int d = flat >> 6, e0 = flat & 63;
    f32x4 s = (f32x4)(0.0f);
    for (int ch = 0; ch < NCH; ch++)
        s += *(const f32x4*)&ctxp[((size_t)ch * 64 + bh) * 4096 + flat];
    const float inv = stats[bh * 64 + d].y;
    __bf16* o = ctxT + (size_t)bh * 4096;
#pragma unroll
    for (int j = 0; j < 4; j++) o[(e0 + j) * 64 + d] = (__bf16)(s[j] * inv);
}

// ---------------------------------------------------------------------------
// pv_fused: per (bh, 256-col tile): q-softmax (unnormalized exp in LDS bf16)
// + MFMA 256x64 K=64 against ctxT, normalize in epilogue, write bf16 outT.
// ---------------------------------------------------------------------------
#define SPS 66   // LDS row stride (bf16)
__global__ __launch_bounds__(256) void pv_fused(__bf16* __restrict__ qkv,
                                                const __bf16* __restrict__ ctxT) {
    __shared__ __align__(16) __bf16 sp[256 * SPS];   // p rows [n][d]
    __shared__ __align__(16) __bf16 sctx[64 * SPS];  // ctxT rows [e][d]
    __shared__ float sinv[256];
    const int tileN = blockIdx.x;
    const int bh = blockIdx.y;
    const int b = bh >> 3, h = bh & 7;
    const int t = threadIdx.x;
    const int n0 = tileN * 256;
    const __bf16* qbase = qkv + (size_t)b * 1536 * L + (size_t)(h * 64) * L;

    {   // stage ctxT (64x64 bf16)
        const int e = t >> 2, c = t & 3;
        const bf16x8* src = (const bf16x8*)(ctxT + ((size_t)bh * 64 + e) * 64 + c * 16);
        *(bf16x8*)&sctx[e * SPS + c * 16] = src[0];
        *(bf16x8*)&sctx[e * SPS + c * 16 + 8] = src[1];
    }

    // read bf16 q column (coalesced across lanes), exp, sum, stage
    float m = -1e30f;
    float qv[64];
#pragma unroll
    for (int d = 0; d < 64; d++) {
        qv[d] = (float)qbase[(size_t)d * L + n0 + t];
        m = fmaxf(m, qv[d]);
    }
    float s = 0.f;
#pragma unroll
    for (int d0 = 0; d0 < 64; d0 += 8) {
        bf16x8 ek;
#pragma unroll
        for (int j = 0; j < 8; j++) {
            float e = __expf(qv[d0 + j] - m);
            s += e;
            ek[j] = (__bf16)e;
        }
        *(bf16x8*)&sp[t * SPS + d0] = ek;
    }
    sinv[t] = 1.0f / s;
    __syncthreads();

    // MFMA: out[n][e] = sum_d p[n][d] * ctxT[e][d]; 4 waves x 64 rows
    const int wave = t >> 6, lane = t & 63;
    const int wm = wave * 64;
    const int fr = lane & 15, kq = (lane >> 4) * 8;
    f32x4 acc[4][4];
#pragma unroll
    for (int i = 0; i < 4; i++)
#pragma unroll
        for (int j = 0; j < 4; j++) acc[i][j] = (f32x4)(0.0f);
#pragma unroll
    for (int kh = 0; kh < 2; kh++) {
        bf16x8 af[4], bfr[4];
#pragma unroll
        for (int i = 0; i < 4; i++)
            af[i] = *(const bf16x8*)&sp[(wm + i * 16 + fr) * SPS + kh * 32 + kq];
#pragma unroll
        for (int j = 0; j < 4; j++)
            bfr[j] = *(const bf16x8*)&sctx[(j * 16 + fr) * SPS + kh * 32 + kq];
#pragma unroll
        for (int i = 0; i < 4; i++)
#pragma unroll
            for (int j = 0; j < 4; j++)
                acc[i][j] = __builtin_amdgcn_mfma_f32_16x16x32_bf16(af[i], bfr[j], acc[i][j], 0, 0, 0);
    }

    // epilogue: normalize by 1/s[n], write bf16 outT[b][n][h*64+e]
    __bf16* ob = qkv + (size_t)b * 1536 * L + (size_t)512 * L;
    const int col = lane & 15, rbase = (lane >> 4) * 4;
#pragma unroll
    for (int i = 0; i < 4; i++) {
#pragma unroll
        for (int r = 0; r < 4; r++) {
            const int nl = wm + i * 16 + rbase + r;
            const float inv = sinv[nl];
            const size_t rowoff = (size_t)(n0 + nl) * 512 + h * 64;
#pragma unroll
            for (int j = 0; j < 4; j++)
                ob[rowoff + j * 16 + col] = (__bf16)(acc[i][j][r] * inv);
        }
    }
}

// ---------------------------------------------------------------------------
extern "C" void kernel_launch(void* const* d_in, const int* in_sizes, int n_in,
                              void* d_out, int out_size, void* d_ws, size_t ws_size,
                              hipStream_t stream) {
    const float* x    = (const float*)d_in[0];
    const float* Wqkv = (const float*)d_in[1];
    const float* Wout = (const float*)d_in[2];
    const float* bout = (const float*)d_in[3];
    float* y = (float*)d_out;

    __bf16* qkv   = (__bf16*)d_ws;                               // 8*1536*4096 bf16
    float*  ctxp  = (float*)(qkv + (size_t)8 * 1536 * L);        // NCH*64*4096 f32
    __bf16* xb    = (__bf16*)(ctxp + (size_t)NCH * 64 * 4096);   // 8*4096*512 bf16
    __bf16* Wqb   = xb + (size_t)8 * 4096 * 512;                 // 1536*512 bf16
    __bf16* Wob   = Wqb + (size_t)1536 * 512;                    // 512*512 bf16
    float2* stats = (float2*)(Wob + (size_t)512 * 512);          // 4096 float2
    __bf16* ctxT  = (__bf16*)(stats + 4096);                     // 64*4096 bf16

    const int convBlocks = (NX8 + NW18 + NW28 + 255) / 256;
    convert_all<<<dim3(convBlocks), 256, 0, stream>>>(x, Wqkv, Wout, xb);

    // qkv[b][o][l] = sum_d Wqkv[o][d] * x[b][l][d]   (M=1536, N=4096, K=512), bf16 out
    gemm_bf16_256<1536, 4096, 512, __bf16><<<dim3(4096 / 256, 1536 / 256, 8), 512, 0, stream>>>(
        Wqb, 0, xb, (size_t)4096 * 512, qkv, (size_t)1536 * 4096, nullptr);

    kstats<<<dim3(4096), 256, 0, stream>>>(qkv, stats);
    context_mfma<<<dim3(NCH, 64), 256, 0, stream>>>(qkv, stats, ctxp);
    ctx_reduce<<<dim3(256), 256, 0, stream>>>(ctxp, stats, ctxT);
    pv_fused<<<dim3(L / 256, 64), 256, 0, stream>>>(qkv, ctxT);

    // y[b][l][d] = sum_c outT[b][l][c] * Wout[d][c] + bout[d]  (M=4096, N=512, K=512), f32 out
    const __bf16* outT = qkv + (size_t)512 * L;
    gemm_bf16_256<4096, 512, 512, float><<<dim3(512 / 256, 4096 / 256, 8), 512, 0, stream>>>(
        outT, (size_t)1536 * L, Wob, 0, y, (size_t)4096 * 512, bout);
}